// Round 6
// baseline (821.188 us; speedup 1.0000x reference)
//
#include <hip/hip_runtime.h>

// y[b, n*DOUT+o] = sum_i x[b,n,i] * W[n,i,o] + bias[n,o]
// B=2048, N=64, DIN=512, DOUT=512, fp32 in/out, bf16 MFMA (fp32 accum).
// R6 = R5 skeleton + {raw barrier w/ counted vmcnt (A-loads fly across),
// A reg-prefetch depth 2, 3 blocks/CU via __launch_bounds__(512,6)}.
// BM=128 BN=256 BK=32, 8 waves (2x4), 48KB LDS double-buffer.

#define NN 64
#define DIN 512
#define DOUT 512
#define BM 128
#define BN 256
#define BK 32
#define KSTEPS (DIN / BK)         // 16
#define ROWSTRIDE (NN * DIN)
#define OUTSTRIDE (NN * DOUT)

typedef __bf16 bf16x8 __attribute__((ext_vector_type(8)));
typedef float f32x4 __attribute__((ext_vector_type(4)));

__device__ __forceinline__ unsigned short f2bf(float f) {
    return __builtin_bit_cast(unsigned short, (__bf16)f);  // RNE
}
__device__ __forceinline__ unsigned int f2bf2(float a, float b) {
    return (unsigned int)f2bf(a) | ((unsigned int)f2bf(b) << 16);
}

typedef const __attribute__((address_space(1))) unsigned int* gas1_t;
typedef __attribute__((address_space(3))) unsigned int* las3_t;
__device__ __forceinline__ void gload_lds16(const void* g, void* l) {
    __builtin_amdgcn_global_load_lds((gas1_t)g, (las3_t)l, 16, 0, 0);
}

// ---- pre-pass: Wt[n][o][i] = bf16(W[n][i][o]) ----
__global__ void wt_transpose_kernel(const float* __restrict__ W,
                                    unsigned short* __restrict__ Wt) {
    __shared__ float tile[32][33];
    const int n  = blockIdx.z;
    const int i0 = blockIdx.x * 32;
    const int o0 = blockIdx.y * 32;
    const float* Wn = W + (size_t)n * DIN * DOUT;
    unsigned short* Wtn = Wt + (size_t)n * DIN * DOUT;
    const int tx = threadIdx.x, ty = threadIdx.y;
#pragma unroll
    for (int q = 0; q < 4; ++q)
        tile[ty + q * 8][tx] = Wn[(size_t)(i0 + ty + q * 8) * DOUT + (o0 + tx)];
    __syncthreads();
#pragma unroll
    for (int q = 0; q < 4; ++q)
        Wtn[(size_t)(o0 + ty + q * 8) * DIN + (i0 + tx)] = f2bf(tile[tx][ty + q * 8]);
}

// ---- main GEMM ----
__global__ __launch_bounds__(512, 6) void node_gemm_kernel(
    const float* __restrict__ X, const unsigned short* __restrict__ Wt,
    const float* __restrict__ Bias, float* __restrict__ Out) {
    // layout: [row][4 slots of 8 shorts], slot' = slot ^ ((row>>1)&3)
    __shared__ unsigned short As[2][BM * BK];   // 2 x 8 KB
    __shared__ unsigned short Bs[2][BN * BK];   // 2 x 16 KB

    // 2048 WGs, bijective XCD swizzle (2048 % 8 == 0)
    const int bid = blockIdx.x;
    const int swz = (bid & 7) * 256 + (bid >> 3);
    const int node  = swz >> 5;
    const int rem   = swz & 31;
    const int mtile = rem >> 1;
    const int ntile = rem & 1;
    const int brow = mtile * BM;
    const int bcol = ntile * BN;

    const int tid  = threadIdx.x;
    const int lane = tid & 63;
    const int w    = tid >> 6;        // 0..7
    const int wm   = w >> 2;          // 0..1
    const int wn   = w & 3;           // 0..3

    const float* Xb = X + (size_t)brow * ROWSTRIDE + node * DIN;
    const unsigned short* Wb = Wt + (size_t)node * DIN * DOUT + (size_t)bcol * DIN;

    // A staging: thread t -> row t>>2 (0..127), slot t&3 (8 floats)
    const int a_r  = tid >> 2;
    const int a_s  = tid & 3;
    const int a_sw = a_s ^ ((a_r >> 1) & 3);
    const float* a_src = Xb + (size_t)a_r * ROWSTRIDE + a_s * 8;
    const int a_dst = a_r * BK + a_sw * 8;   // shorts

    // B staging via gload_lds: inst i = q*8+w covers B-rows 16i..16i+15
    const unsigned short* b_src[2];
    int b_dst[2];
#pragma unroll
    for (int q = 0; q < 2; ++q) {
        const int i = q * 8 + w;
        const int c = i * 16 + (lane >> 2);
        const int s = lane & 3;
        const int gs = s ^ ((c >> 1) & 3);       // inverse slot swizzle on source
        b_src[q] = Wb + (size_t)c * DIN + gs * 8;
        b_dst[q] = i * 512;                      // shorts (1KB per inst)
    }

    // fragment read offsets (swizzled K-slot)
    const int arow = lane & 15;
    const int akk  = lane >> 4;
    const int kswz = akk ^ ((arow >> 1) & 3);
    const int afrag = (wm * 64 + arow) * BK + kswz * 8;
    const int bfrag = (wn * 64 + arow) * BK + kswz * 8;

    f32x4 acc[4][4] = {};
    float4 av0[2], av1[2];   // 2-deep A register prefetch

    auto stageB = [&](int buf, int kt) {
#pragma unroll
        for (int q = 0; q < 2; ++q)
            gload_lds16(b_src[q] + kt * BK, &Bs[buf][b_dst[q]]);
    };
    auto loadA = [&](int kt, int set) {
        const float* p = a_src + kt * BK;
        av0[set] = *reinterpret_cast<const float4*>(p);
        av1[set] = *reinterpret_cast<const float4*>(p + 4);
    };
    auto storeA = [&](int buf, int set) {
        uint4 pk;
        pk.x = f2bf2(av0[set].x, av0[set].y);
        pk.y = f2bf2(av0[set].z, av0[set].w);
        pk.z = f2bf2(av1[set].x, av1[set].y);
        pk.w = f2bf2(av1[set].z, av1[set].w);
        *reinterpret_cast<uint4*>(&As[buf][a_dst]) = pk;
    };
    auto compute = [&](int buf) {
        bf16x8 af[4], bq[4];
#pragma unroll
        for (int m = 0; m < 4; ++m)
            af[m] = *reinterpret_cast<const bf16x8*>(&As[buf][afrag + m * 16 * BK]);
#pragma unroll
        for (int n = 0; n < 4; ++n)
            bq[n] = *reinterpret_cast<const bf16x8*>(&Bs[buf][bfrag + n * 16 * BK]);
#pragma unroll
        for (int m = 0; m < 4; ++m)
#pragma unroll
            for (int n = 0; n < 4; ++n)
                acc[m][n] = __builtin_amdgcn_mfma_f32_16x16x32_bf16(af[m], bq[n], acc[m][n], 0, 0, 0);
    };

    // prologue: A(0) -> LDS, A(1) in regs; B(0) staged. Full drain once.
    loadA(0, 0);
    loadA(1, 1);
    stageB(0, 0);
    storeA(0, 0);
    __syncthreads();

    // main loop, fully unrolled: per iter kt (buf = kt&1):
    //   stageB(kt+1) [2 DMA] ; loadA(kt+2)->set kt&1 [2 loads, fly across barrier]
    //   compute(kt) ; storeA(kt+1) from set (kt+1)&1 (loaded ≥1 iter ago)
    //   s_waitcnt vmcnt(#A-loads-in-flight) lgkmcnt(0) ; s_barrier
#pragma unroll
    for (int kt = 0; kt < KSTEPS; ++kt) {
        const int buf = kt & 1;
        if (kt + 1 < KSTEPS) stageB(buf ^ 1, kt + 1);
        if (kt + 2 < KSTEPS) loadA(kt + 2, kt & 1);
        compute(buf);
        if (kt + 1 < KSTEPS) storeA(buf ^ 1, (kt + 1) & 1);
        if (kt + 1 < KSTEPS) {
            if (kt + 2 < KSTEPS)
                asm volatile("s_waitcnt vmcnt(2) lgkmcnt(0)" ::: "memory");
            else
                asm volatile("s_waitcnt vmcnt(0) lgkmcnt(0)" ::: "memory");
            __builtin_amdgcn_s_barrier();
        }
    }

    // epilogue: D mapping col = lane&15, row = (lane>>4)*4 + j
    const float* bn = Bias + node * DOUT + bcol;
    float* outb = Out + (size_t)brow * OUTSTRIDE + node * DOUT + bcol;
#pragma unroll
    for (int n = 0; n < 4; ++n) {
        const int col = wn * 64 + n * 16 + arow;
        const float bias = bn[col];
#pragma unroll
        for (int m = 0; m < 4; ++m) {
            const int r0 = wm * 64 + m * 16 + akk * 4;
#pragma unroll
            for (int j = 0; j < 4; ++j)
                outb[(size_t)(r0 + j) * OUTSTRIDE + col] = acc[m][n][j] + bias;
        }
    }
}

extern "C" void kernel_launch(void* const* d_in, const int* in_sizes, int n_in,
                              void* d_out, int out_size, void* d_ws, size_t ws_size,
                              hipStream_t stream) {
    const float* x = (const float*)d_in[0];      // [2048, 64, 512]
    const float* W = (const float*)d_in[1];      // [64, 512, 512]
    const float* b = (const float*)d_in[2];      // [64, 512]
    float* out = (float*)d_out;                  // [2048, 64*512]
    unsigned short* Wt = (unsigned short*)d_ws;  // bf16 [64][512][512] = 33.5 MB

    wt_transpose_kernel<<<dim3(DIN / 32, DOUT / 32, NN), dim3(32, 8), 0, stream>>>(W, Wt);
    node_gemm_kernel<<<dim3(2048), dim3(512), 0, stream>>>(x, Wt, b, out);
}

// Round 7
// 270.269 us; speedup vs baseline: 3.0384x; 3.0384x over previous
//
#include <hip/hip_runtime.h>

// y[b, n*DOUT+o] = sum_i x[b,n,i] * W[n,i,o] + bias[n,o]
// B=2048, N=64, DIN=512, DOUT=512, fp32 in/out, bf16 MFMA (fp32 accum).
// R7 = R6 with __launch_bounds__(512,4): R6's (512,6) capped VGPR at ~85 and
// spilled the 64-reg accumulator to scratch (VGPR 40, WRITE 1.9GB). Structure:
// raw barrier + counted vmcnt (A-loads fly across a full iteration), A reg
// prefetch depth 2, B via global_load_lds(16). BM=128 BN=256 BK=32, 8 waves.

#define NN 64
#define DIN 512
#define DOUT 512
#define BM 128
#define BN 256
#define BK 32
#define KSTEPS (DIN / BK)         // 16
#define ROWSTRIDE (NN * DIN)
#define OUTSTRIDE (NN * DOUT)

typedef __bf16 bf16x8 __attribute__((ext_vector_type(8)));
typedef float f32x4 __attribute__((ext_vector_type(4)));

__device__ __forceinline__ unsigned short f2bf(float f) {
    return __builtin_bit_cast(unsigned short, (__bf16)f);  // RNE
}
__device__ __forceinline__ unsigned int f2bf2(float a, float b) {
    return (unsigned int)f2bf(a) | ((unsigned int)f2bf(b) << 16);
}

typedef const __attribute__((address_space(1))) unsigned int* gas1_t;
typedef __attribute__((address_space(3))) unsigned int* las3_t;
__device__ __forceinline__ void gload_lds16(const void* g, void* l) {
    __builtin_amdgcn_global_load_lds((gas1_t)g, (las3_t)l, 16, 0, 0);
}

// ---- pre-pass: Wt[n][o][i] = bf16(W[n][i][o]) ----
__global__ void wt_transpose_kernel(const float* __restrict__ W,
                                    unsigned short* __restrict__ Wt) {
    __shared__ float tile[32][33];
    const int n  = blockIdx.z;
    const int i0 = blockIdx.x * 32;
    const int o0 = blockIdx.y * 32;
    const float* Wn = W + (size_t)n * DIN * DOUT;
    unsigned short* Wtn = Wt + (size_t)n * DIN * DOUT;
    const int tx = threadIdx.x, ty = threadIdx.y;
#pragma unroll
    for (int q = 0; q < 4; ++q)
        tile[ty + q * 8][tx] = Wn[(size_t)(i0 + ty + q * 8) * DOUT + (o0 + tx)];
    __syncthreads();
#pragma unroll
    for (int q = 0; q < 4; ++q)
        Wtn[(size_t)(o0 + ty + q * 8) * DIN + (i0 + tx)] = f2bf(tile[tx][ty + q * 8]);
}

// ---- main GEMM ----
__global__ __launch_bounds__(512, 4) void node_gemm_kernel(
    const float* __restrict__ X, const unsigned short* __restrict__ Wt,
    const float* __restrict__ Bias, float* __restrict__ Out) {
    // layout: [row][4 slots of 8 shorts], slot' = slot ^ ((row>>1)&3)
    __shared__ unsigned short As[2][BM * BK];   // 2 x 8 KB
    __shared__ unsigned short Bs[2][BN * BK];   // 2 x 16 KB

    // 2048 WGs, bijective XCD swizzle (2048 % 8 == 0)
    const int bid = blockIdx.x;
    const int swz = (bid & 7) * 256 + (bid >> 3);
    const int node  = swz >> 5;
    const int rem   = swz & 31;
    const int mtile = rem >> 1;
    const int ntile = rem & 1;
    const int brow = mtile * BM;
    const int bcol = ntile * BN;

    const int tid  = threadIdx.x;
    const int lane = tid & 63;
    const int w    = tid >> 6;        // 0..7
    const int wm   = w >> 2;          // 0..1
    const int wn   = w & 3;           // 0..3

    const float* Xb = X + (size_t)brow * ROWSTRIDE + node * DIN;
    const unsigned short* Wb = Wt + (size_t)node * DIN * DOUT + (size_t)bcol * DIN;

    // A staging: thread t -> row t>>2 (0..127), slot t&3 (8 floats)
    const int a_r  = tid >> 2;
    const int a_s  = tid & 3;
    const int a_sw = a_s ^ ((a_r >> 1) & 3);
    const float* a_src = Xb + (size_t)a_r * ROWSTRIDE + a_s * 8;
    const int a_dst = a_r * BK + a_sw * 8;   // shorts

    // B staging via gload_lds: inst i = q*8+w covers B-rows 16i..16i+15
    const unsigned short* b_src[2];
    int b_dst[2];
#pragma unroll
    for (int q = 0; q < 2; ++q) {
        const int i = q * 8 + w;
        const int c = i * 16 + (lane >> 2);
        const int s = lane & 3;
        const int gs = s ^ ((c >> 1) & 3);       // inverse slot swizzle on source
        b_src[q] = Wb + (size_t)c * DIN + gs * 8;
        b_dst[q] = i * 512;                      // shorts (1KB per inst)
    }

    // fragment read offsets (swizzled K-slot)
    const int arow = lane & 15;
    const int akk  = lane >> 4;
    const int kswz = akk ^ ((arow >> 1) & 3);
    const int afrag = (wm * 64 + arow) * BK + kswz * 8;
    const int bfrag = (wn * 64 + arow) * BK + kswz * 8;

    f32x4 acc[4][4] = {};
    float4 av0[2], av1[2];   // 2-deep A register prefetch

    auto stageB = [&](int buf, int kt) {
#pragma unroll
        for (int q = 0; q < 2; ++q)
            gload_lds16(b_src[q] + kt * BK, &Bs[buf][b_dst[q]]);
    };
    auto loadA = [&](int kt, int set) {
        const float* p = a_src + kt * BK;
        av0[set] = *reinterpret_cast<const float4*>(p);
        av1[set] = *reinterpret_cast<const float4*>(p + 4);
    };
    auto storeA = [&](int buf, int set) {
        uint4 pk;
        pk.x = f2bf2(av0[set].x, av0[set].y);
        pk.y = f2bf2(av0[set].z, av0[set].w);
        pk.z = f2bf2(av1[set].x, av1[set].y);
        pk.w = f2bf2(av1[set].z, av1[set].w);
        *reinterpret_cast<uint4*>(&As[buf][a_dst]) = pk;
    };
    auto compute = [&](int buf) {
        bf16x8 af[4], bq[4];
#pragma unroll
        for (int m = 0; m < 4; ++m)
            af[m] = *reinterpret_cast<const bf16x8*>(&As[buf][afrag + m * 16 * BK]);
#pragma unroll
        for (int n = 0; n < 4; ++n)
            bq[n] = *reinterpret_cast<const bf16x8*>(&Bs[buf][bfrag + n * 16 * BK]);
#pragma unroll
        for (int m = 0; m < 4; ++m)
#pragma unroll
            for (int n = 0; n < 4; ++n)
                acc[m][n] = __builtin_amdgcn_mfma_f32_16x16x32_bf16(af[m], bq[n], acc[m][n], 0, 0, 0);
    };

    // prologue: A(0) -> LDS, A(1) in regs; B(0) staged. Full drain once.
    loadA(0, 0);
    loadA(1, 1);
    stageB(0, 0);
    storeA(0, 0);
    __syncthreads();

    // main loop, fully unrolled: per iter kt (buf = kt&1):
    //   stageB(kt+1) [2 DMA] ; loadA(kt+2)->set kt&1 [2 loads, fly across barrier]
    //   compute(kt) ; storeA(kt+1) from set (kt+1)&1 (loaded one iter ago)
    //   s_waitcnt vmcnt(#A-loads-in-flight) lgkmcnt(0) ; s_barrier
#pragma unroll
    for (int kt = 0; kt < KSTEPS; ++kt) {
        const int buf = kt & 1;
        if (kt + 1 < KSTEPS) stageB(buf ^ 1, kt + 1);
        if (kt + 2 < KSTEPS) loadA(kt + 2, kt & 1);
        compute(buf);
        if (kt + 1 < KSTEPS) storeA(buf ^ 1, (kt + 1) & 1);
        if (kt + 1 < KSTEPS) {
            if (kt + 2 < KSTEPS)
                asm volatile("s_waitcnt vmcnt(2) lgkmcnt(0)" ::: "memory");
            else
                asm volatile("s_waitcnt vmcnt(0) lgkmcnt(0)" ::: "memory");
            __builtin_amdgcn_s_barrier();
        }
    }

    // epilogue: D mapping col = lane&15, row = (lane>>4)*4 + j
    const float* bn = Bias + node * DOUT + bcol;
    float* outb = Out + (size_t)brow * OUTSTRIDE + node * DOUT + bcol;
#pragma unroll
    for (int n = 0; n < 4; ++n) {
        const int col = wn * 64 + n * 16 + arow;
        const float bias = bn[col];
#pragma unroll
        for (int m = 0; m < 4; ++m) {
            const int r0 = wm * 64 + m * 16 + akk * 4;
#pragma unroll
            for (int j = 0; j < 4; ++j)
                outb[(size_t)(r0 + j) * OUTSTRIDE + col] = acc[m][n][j] + bias;
        }
    }
}

extern "C" void kernel_launch(void* const* d_in, const int* in_sizes, int n_in,
                              void* d_out, int out_size, void* d_ws, size_t ws_size,
                              hipStream_t stream) {
    const float* x = (const float*)d_in[0];      // [2048, 64, 512]
    const float* W = (const float*)d_in[1];      // [64, 512, 512]
    const float* b = (const float*)d_in[2];      // [64, 512]
    float* out = (float*)d_out;                  // [2048, 64*512]
    unsigned short* Wt = (unsigned short*)d_ws;  // bf16 [64][512][512] = 33.5 MB

    wt_transpose_kernel<<<dim3(DIN / 32, DOUT / 32, NN), dim3(32, 8), 0, stream>>>(W, Wt);
    node_gemm_kernel<<<dim3(2048), dim3(512), 0, stream>>>(x, Wt, b, out);
}

// Round 8
// 235.160 us; speedup vs baseline: 3.4920x; 1.1493x over previous
//
#include <hip/hip_runtime.h>

// y[b, n*DOUT+o] = sum_i x[b,n,i] * W[n,i,o] + bias[n,o]
// B=2048, N=64, DIN=512, DOUT=512, fp32 in/out, bf16 MFMA (fp32 accum).
// R8: m97-geometry. BM=BN=128, BK=32, 256 threads (4 waves 2x2), 32KB LDS
// double-buffer -> 4 blocks/CU (staggered drains: the latency-hiding m97 has
// and R5's 2x512-thread lockstep blocks lack). A reg-staged bf16 (native cvt),
// B via global_load_lds(16) with source slot-swizzle. Plain __syncthreads loop.

#define NN 64
#define DIN 512
#define DOUT 512
#define BM 128
#define BN 128
#define BK 32
#define KSTEPS (DIN / BK)         // 16
#define ROWSTRIDE (NN * DIN)
#define OUTSTRIDE (NN * DOUT)

typedef __bf16 bf16x8 __attribute__((ext_vector_type(8)));
typedef float f32x4 __attribute__((ext_vector_type(4)));

__device__ __forceinline__ unsigned short f2bf(float f) {
    return __builtin_bit_cast(unsigned short, (__bf16)f);  // RNE
}
__device__ __forceinline__ unsigned int f2bf2(float a, float b) {
    return (unsigned int)f2bf(a) | ((unsigned int)f2bf(b) << 16);
}

typedef const __attribute__((address_space(1))) unsigned int* gas1_t;
typedef __attribute__((address_space(3))) unsigned int* las3_t;
__device__ __forceinline__ void gload_lds16(const void* g, void* l) {
    __builtin_amdgcn_global_load_lds((gas1_t)g, (las3_t)l, 16, 0, 0);
}

// ---- pre-pass: Wt[n][o][i] = bf16(W[n][i][o]) ----
__global__ void wt_transpose_kernel(const float* __restrict__ W,
                                    unsigned short* __restrict__ Wt) {
    __shared__ float tile[32][33];
    const int n  = blockIdx.z;
    const int i0 = blockIdx.x * 32;
    const int o0 = blockIdx.y * 32;
    const float* Wn = W + (size_t)n * DIN * DOUT;
    unsigned short* Wtn = Wt + (size_t)n * DIN * DOUT;
    const int tx = threadIdx.x, ty = threadIdx.y;
#pragma unroll
    for (int q = 0; q < 4; ++q)
        tile[ty + q * 8][tx] = Wn[(size_t)(i0 + ty + q * 8) * DOUT + (o0 + tx)];
    __syncthreads();
#pragma unroll
    for (int q = 0; q < 4; ++q)
        Wtn[(size_t)(o0 + ty + q * 8) * DIN + (i0 + tx)] = f2bf(tile[tx][ty + q * 8]);
}

// ---- main GEMM ----
__global__ __launch_bounds__(256, 4) void node_gemm_kernel(
    const float* __restrict__ X, const unsigned short* __restrict__ Wt,
    const float* __restrict__ Bias, float* __restrict__ Out) {
    // layout: [row][4 slots of 8 shorts], slot' = slot ^ ((row>>1)&3)
    __shared__ unsigned short As[2][BM * BK];   // 2 x 8 KB
    __shared__ unsigned short Bs[2][BN * BK];   // 2 x 8 KB

    // 4096 WGs, bijective XCD swizzle (4096 % 8 == 0); ntile-minor so the 4
    // blocks sharing an x-panel run concurrently on the same XCD.
    const int bid = blockIdx.x;
    const int swz = (bid & 7) * 512 + (bid >> 3);
    const int node  = swz >> 6;
    const int rem   = swz & 63;
    const int mtile = rem >> 2;
    const int ntile = rem & 3;
    const int brow = mtile * BM;
    const int bcol = ntile * BN;

    const int tid  = threadIdx.x;
    const int lane = tid & 63;
    const int w    = tid >> 6;        // 0..3
    const int wm   = w >> 1;          // 0..1
    const int wn   = w & 1;           // 0..1

    const float* Xb = X + (size_t)brow * ROWSTRIDE + node * DIN;
    const unsigned short* Wb = Wt + (size_t)node * DIN * DOUT + (size_t)bcol * DIN;

    // A staging: thread t -> row t>>2 (0..63 base, x2 halves), slot t&3 (8 floats)
    // 128 rows x 4 slots = 512 slots; 256 threads do 2 each (rows r and r+64)
    const int a_r  = tid >> 2;        // 0..63
    const int a_s  = tid & 3;
    const float* a_src0 = Xb + (size_t)a_r * ROWSTRIDE + a_s * 8;
    const float* a_src1 = Xb + (size_t)(a_r + 64) * ROWSTRIDE + a_s * 8;
    const int a_dst0 = a_r * BK + (a_s ^ ((a_r >> 1) & 3)) * 8;          // shorts
    const int a_dst1 = (a_r + 64) * BK + (a_s ^ (((a_r + 64) >> 1) & 3)) * 8;

    // B staging via gload_lds: inst i = q*4+w (q<2) covers B-cols 16i..16i+15
    const unsigned short* b_src[2];
    int b_dst[2];
#pragma unroll
    for (int q = 0; q < 2; ++q) {
        const int i = q * 4 + w;
        const int c = i * 16 + (lane >> 2);      // col (B-row in LDS)
        const int s = lane & 3;
        const int gs = s ^ ((c >> 1) & 3);       // inverse slot swizzle on source
        b_src[q] = Wb + (size_t)c * DIN + gs * 8;
        b_dst[q] = i * 512;                      // shorts (1KB per inst)
    }

    // fragment read offsets (swizzled K-slot)
    const int arow = lane & 15;
    const int akk  = lane >> 4;
    const int kswz = akk ^ ((arow >> 1) & 3);
    const int afrag = (wm * 64 + arow) * BK + kswz * 8;
    const int bfrag = (wn * 64 + arow) * BK + kswz * 8;

    f32x4 acc[4][4] = {};
    float4 av0, av1, av2, av3;

    auto stageB = [&](int buf, int kt) {
#pragma unroll
        for (int q = 0; q < 2; ++q)
            gload_lds16(b_src[q] + kt * BK, &Bs[buf][b_dst[q]]);
    };
    auto loadA = [&](int kt) {
        const float* p0 = a_src0 + kt * BK;
        const float* p1 = a_src1 + kt * BK;
        av0 = *reinterpret_cast<const float4*>(p0);
        av1 = *reinterpret_cast<const float4*>(p0 + 4);
        av2 = *reinterpret_cast<const float4*>(p1);
        av3 = *reinterpret_cast<const float4*>(p1 + 4);
    };
    auto storeA = [&](int buf) {
        uint4 pk;
        pk.x = f2bf2(av0.x, av0.y);
        pk.y = f2bf2(av0.z, av0.w);
        pk.z = f2bf2(av1.x, av1.y);
        pk.w = f2bf2(av1.z, av1.w);
        *reinterpret_cast<uint4*>(&As[buf][a_dst0]) = pk;
        pk.x = f2bf2(av2.x, av2.y);
        pk.y = f2bf2(av2.z, av2.w);
        pk.z = f2bf2(av3.x, av3.y);
        pk.w = f2bf2(av3.z, av3.w);
        *reinterpret_cast<uint4*>(&As[buf][a_dst1]) = pk;
    };

    // prologue
    stageB(0, 0);
    loadA(0);
    storeA(0);
    __syncthreads();

    int buf = 0;
    for (int kt = 0; kt < KSTEPS; ++kt) {
        const bool more = (kt < KSTEPS - 1);
        if (more) {                    // issue next-tile loads before compute
            stageB(buf ^ 1, kt + 1);
            loadA(kt + 1);
        }
        bf16x8 af[4], bq[4];
#pragma unroll
        for (int m = 0; m < 4; ++m)
            af[m] = *reinterpret_cast<const bf16x8*>(&As[buf][afrag + m * 16 * BK]);
#pragma unroll
        for (int n = 0; n < 4; ++n)
            bq[n] = *reinterpret_cast<const bf16x8*>(&Bs[buf][bfrag + n * 16 * BK]);
#pragma unroll
        for (int m = 0; m < 4; ++m)
#pragma unroll
            for (int n = 0; n < 4; ++n)
                acc[m][n] = __builtin_amdgcn_mfma_f32_16x16x32_bf16(af[m], bq[n], acc[m][n], 0, 0, 0);
        if (more) storeA(buf ^ 1);     // cvt + LDS write after MFMA (hides HBM latency)
        __syncthreads();
        buf ^= 1;
    }

    // epilogue: D mapping col = lane&15, row = (lane>>4)*4 + j
    const float* bn = Bias + node * DOUT + bcol;
    float* outb = Out + (size_t)brow * OUTSTRIDE + node * DOUT + bcol;
#pragma unroll
    for (int n = 0; n < 4; ++n) {
        const int col = wn * 64 + n * 16 + arow;
        const float bias = bn[col];
#pragma unroll
        for (int m = 0; m < 4; ++m) {
            const int r0 = wm * 64 + m * 16 + akk * 4;
#pragma unroll
            for (int j = 0; j < 4; ++j)
                outb[(size_t)(r0 + j) * OUTSTRIDE + col] = acc[m][n][j] + bias;
        }
    }
}

extern "C" void kernel_launch(void* const* d_in, const int* in_sizes, int n_in,
                              void* d_out, int out_size, void* d_ws, size_t ws_size,
                              hipStream_t stream) {
    const float* x = (const float*)d_in[0];      // [2048, 64, 512]
    const float* W = (const float*)d_in[1];      // [64, 512, 512]
    const float* b = (const float*)d_in[2];      // [64, 512]
    float* out = (float*)d_out;                  // [2048, 64*512]
    unsigned short* Wt = (unsigned short*)d_ws;  // bf16 [64][512][512] = 33.5 MB

    wt_transpose_kernel<<<dim3(DIN / 32, DOUT / 32, NN), dim3(32, 8), 0, stream>>>(W, Wt);
    node_gemm_kernel<<<dim3(4096), dim3(256), 0, stream>>>(x, Wt, b, out);
}